// Round 2
// baseline (692.331 us; speedup 1.0000x reference)
//
#include <hip/hip_runtime.h>
#include <math.h>
#include <stdint.h>

#define NQ 12
#define DIMK 256
#define NCTRL 25
#define TPB 256
#define TILE 64          // points per tile; 64 rows * 1KB = 64KB per buffer

// ---------------------------------------------------------------------------
// Round 2: counted-vmcnt pipeline (T4).
//  * Persistent blocks, 1/CU, grid-stride over 64-point tiles (as round 1).
//  * emb staged via global_load_lds width=16 (1KB/row/instruction, zero VGPR).
//  * Rows wave-private -> NO barriers in main loop; waves drift freely.
//  * NEW: instead of one coarse vmcnt(0) per tile, issue next tile's 16 loads
//    at loop top (32 outstanding/wave), then interleave counted waits with
//    the four 4-row compute sub-phases:
//       vmcnt(28) -> rows 0-3 of current tile landed -> compute s=0
//       vmcnt(24) -> rows 4-7 -> s=1 ... vmcnt(16) -> s=3
//    Per-wave outstanding never drops below 16 -> the per-CU request stream
//    is continuous (vs bursty round-1: issue-16/drain-to-0), keeping HBM at
//    its achievable ceiling. vmcnt retires oldest-first (in-order VMEM).
//  * W in 192 VGPRs (lane h owns k-slice {4h+64m..+3}); DPP-only reductions
//    keep the DS pipe free for the e-stream.
// ---------------------------------------------------------------------------

template<int CTRL>
__device__ __forceinline__ float dpp_red(float v) {
    int t = __builtin_amdgcn_mov_dpp(__float_as_int(v), CTRL, 0xF, 0xF, 1);
    return v + __int_as_float(t);
}

// Sum across the 16-lane DPP row; every lane ends with the full sum.
__device__ __forceinline__ float row16_sum(float v) {
    v = dpp_red<0xB1>(v);    // quad_perm(1,0,3,2)
    v = dpp_red<0x4E>(v);    // quad_perm(2,3,0,1)
    v = dpp_red<0x124>(v);   // row_ror:4
    v = dpp_red<0x128>(v);   // row_ror:8
    return v;
}

// Stage this wave's 16 rows of one tile into LDS (1KB per instruction).
__device__ __forceinline__ void stage_tile(const float* __restrict__ emb,
                                           float* dstbase, int p0,
                                           int w, int lane, int nm1) {
    #pragma unroll
    for (int j = 0; j < 16; ++j) {
        const int row = (w << 4) + j;
        int grow = p0 + row;
        grow = grow > nm1 ? nm1 : grow;           // clamp: safe read, discarded
        const float* src = emb + (size_t)grow * DIMK + (lane << 2);
        float* dst = dstbase + row * DIMK;
        __builtin_amdgcn_global_load_lds(
            (const __attribute__((address_space(1))) void*)src,
            (__attribute__((address_space(3))) void*)dst,
            16, 0, 0);
    }
}

__global__ __launch_bounds__(TPB, 1) void kan_bspline_kernel(
    const float* __restrict__ emb,
    const float* __restrict__ W,
    const float* __restrict__ b_inner,
    const float* __restrict__ inner_scale,
    const float* __restrict__ coeffs,
    const float* __restrict__ a_out,
    const float* __restrict__ b_out,
    float* __restrict__ out,
    int n)
{
    __shared__ __align__(16) float sE[2 * TILE * DIMK];   // 128 KB, dbuf
    __shared__ float sC[NQ * NCTRL];                      // 1.2 KB

    const int tid  = threadIdx.x;
    const int w    = tid >> 6;       // wave 0..3
    const int lane = tid & 63;
    const int cl   = lane >> 4;      // 16-lane cluster 0..3
    const int h    = lane & 15;      // lane within cluster
    const int nm1  = n - 1;
    const int ntiles = (n + TILE - 1) / TILE;
    const int G = (int)gridDim.x;

    for (int i = tid; i < NQ * NCTRL; i += TPB) sC[i] = coeffs[i];
    __syncthreads();                 // only barrier in the kernel

    // W slice in registers: lane h owns k = 4h + 64m + t, all 12 q -> 192 VGPR
    float4 wq[NQ][4];
    #pragma unroll
    for (int q = 0; q < NQ; ++q)
        #pragma unroll
        for (int m = 0; m < 4; ++m)
            wq[q][m] = *(const float4*)(W + q * DIMK + (m << 6) + (h << 2));

    const float b_h = (h < NQ) ? b_inner[h] : 0.0f;
    const float a_h = (h < NQ) ? a_out[h]   : 0.0f;
    const float scale = inner_scale[0];
    const float bout  = b_out[0];

    const float hh  = 1.0f / 22.0f;
    const float i1h = 22.0f;
    const float i2h = 11.0f;
    const float i3h = 22.0f / 3.0f;

    // One 4-row compute sub-phase (rows (w<<4)+(s<<2)+cl of buffer bp).
#define COMP(S)                                                               \
    {                                                                         \
        const int r = (w << 4) + ((S) << 2) + cl;                             \
        const float* ep = bp + r * DIMK + (h << 2);                           \
        const float4 e0 = *(const float4*)(ep);                               \
        const float4 e1 = *(const float4*)(ep + 64);                          \
        const float4 e2 = *(const float4*)(ep + 128);                         \
        const float4 e3 = *(const float4*)(ep + 192);                         \
        float red[NQ];                                                        \
        _Pragma("unroll")                                                     \
        for (int q = 0; q < NQ; ++q) {                                        \
            float acc;                                                        \
            acc  = e0.x * wq[q][0].x;  acc += e0.y * wq[q][0].y;              \
            acc += e0.z * wq[q][0].z;  acc += e0.w * wq[q][0].w;              \
            acc += e1.x * wq[q][1].x;  acc += e1.y * wq[q][1].y;              \
            acc += e1.z * wq[q][1].z;  acc += e1.w * wq[q][1].w;              \
            acc += e2.x * wq[q][2].x;  acc += e2.y * wq[q][2].y;              \
            acc += e2.z * wq[q][2].z;  acc += e2.w * wq[q][2].w;              \
            acc += e3.x * wq[q][3].x;  acc += e3.y * wq[q][3].y;              \
            acc += e3.z * wq[q][3].z;  acc += e3.w * wq[q][3].w;              \
            red[q] = row16_sum(acc);                                          \
        }                                                                     \
        float uq = 0.0f;                                                      \
        _Pragma("unroll")                                                     \
        for (int q = 0; q < NQ; ++q) uq = (h == q) ? red[q] : uq;             \
        const float uu = uq + b_h;                                            \
        const float sv = 0.5f * tanhf(scale * uu) + 0.5f;                     \
        int iv = (int)(sv * 22.0f);                                           \
        iv = iv > 21 ? 21 : iv;  iv = iv < 0 ? 0 : iv;                        \
        const float fiv = (float)iv;                                          \
        const float l1 = sv - fiv * hh;                                       \
        const float l2 = sv - fmaxf(fiv - 1.0f, 0.0f) * hh;                   \
        const float l3 = sv - fmaxf(fiv - 2.0f, 0.0f) * hh;                   \
        const float r1 = fminf((fiv + 1.0f) * hh, 1.0f) - sv;                 \
        const float r2 = fminf((fiv + 2.0f) * hh, 1.0f) - sv;                 \
        const float r3 = fminf((fiv + 3.0f) * hh, 1.0f) - sv;                 \
        const float inv_b = (iv >= 1) ? i2h : i1h;                            \
        const float inv_c = (iv <= 20) ? i2h : i1h;                           \
        const float inv_d = (iv >= 2) ? i3h : ((iv >= 1) ? i2h : i1h);        \
        const float inv_e = (iv >= 1 && iv <= 20) ? i3h : i2h;                \
        const float inv_f = (iv <= 19) ? i3h : ((iv <= 20) ? i2h : i1h);      \
        float tmp, saved;                                                     \
        tmp = i1h;                                                            \
        float N0v = r1 * tmp;                                                 \
        float N1v = l1 * tmp;                                                 \
        tmp   = N0v * inv_b;  N0v = r1 * tmp;  saved = l2 * tmp;              \
        tmp   = N1v * inv_c;  N1v = saved + r2 * tmp;                         \
        float N2v = l1 * tmp;                                                 \
        tmp   = N0v * inv_d;  N0v = r1 * tmp;  saved = l3 * tmp;              \
        tmp   = N1v * inv_e;  N1v = saved + r2 * tmp;  saved = l2 * tmp;      \
        tmp   = N2v * inv_f;  N2v = saved + r3 * tmp;                         \
        float N3v = l1 * tmp;                                                 \
        const int qe = (h < NQ) ? h : 0;                                      \
        const float* cq = sC + qe * NCTRL + iv;                               \
        const float phi = N0v * cq[0] + N1v * cq[1] + N2v * cq[2] + N3v * cq[3];\
        float part = a_h * phi;                                               \
        part = row16_sum(part);                                               \
        if (h == 0) {                                                         \
            const int pidx = p0 + r;                                          \
            if (pidx < n) out[pidx] = part + bout;                            \
        }                                                                     \
    }

#define WAIT(N) asm volatile("s_waitcnt vmcnt(" #N ")" ::: "memory")

    int buf = 0;
    const int t0 = blockIdx.x;       // grid <= ntiles guaranteed by launcher
    stage_tile(emb, sE, t0 * TILE, w, lane, nm1);

    for (int t = t0; t < ntiles; t += G) {
        const int tn = t + G;
        const float* bp = sE + buf * (TILE * DIMK);
        const int p0 = t * TILE;

        if (tn < ntiles) {
            // issue next tile's 16 loads first: 32 outstanding/wave, then
            // counted waits interleave delivery of tile t with its compute.
            stage_tile(emb, sE + ((buf ^ 1) * (TILE * DIMK)), tn * TILE, w, lane, nm1);
            WAIT(28); COMP(0);
            WAIT(24); COMP(1);
            WAIT(20); COMP(2);
            WAIT(16); COMP(3);
        } else {
            // last tile for this block: no prefetch, drain 16 -> 0
            WAIT(12); COMP(0);
            WAIT(8);  COMP(1);
            WAIT(4);  COMP(2);
            WAIT(0);  COMP(3);
        }
        buf ^= 1;
    }
#undef COMP
#undef WAIT
}

extern "C" void kernel_launch(void* const* d_in, const int* in_sizes, int n_in,
                              void* d_out, int out_size, void* d_ws, size_t ws_size,
                              hipStream_t stream) {
    const float* emb         = (const float*)d_in[0];
    const float* W           = (const float*)d_in[1];
    const float* b_inner     = (const float*)d_in[2];
    const float* inner_scale = (const float*)d_in[3];
    const float* coeffs      = (const float*)d_in[4];
    const float* a_out       = (const float*)d_in[5];
    const float* b_out       = (const float*)d_in[6];
    float* out = (float*)d_out;

    const int n = in_sizes[0] / DIMK;
    const int ntiles = (n + TILE - 1) / TILE;
    int grid = ntiles < 256 ? ntiles : 256;   // persistent: 1 block per CU
    kan_bspline_kernel<<<grid, TPB, 0, stream>>>(
        emb, W, b_inner, inner_scale, coeffs, a_out, b_out, out, n);
}